// Round 1
// baseline (448.789 us; speedup 1.0000x reference)
//
#include <hip/hip_runtime.h>
#include <math.h>

#define IN_C   256
#define OUT_C  512
#define HW     3136
#define W_     56
#define D_     2304
#define TBL    16

// ws layout (4-byte units):
// [0,2304)      max_row (float)
// [2304,2816)   hashk (int)
// [2816]        qidx (int)
// [2817]        count_eff (int)
// [2818]        scale_mul (float)
// [2819,3331)   active (int)
// [3331,3843)   flags (int, 1 = channel is computed by conv)
// byte 16384+   Wc: bf16 weights, compacted active rows [512][2304]
// byte 2375680+ Xb: bf16 padded NHWC-ish x [cg=8][n=16][yp=58][wp=58][c=32]

#define XB_OFF 2375680ULL
#define XB_ROW 1856            // ushorts per (cg,n,yp) row: 58*32

typedef __attribute__((ext_vector_type(8))) __bf16 bf16x8;
typedef __attribute__((ext_vector_type(4))) float f32x4;

__device__ __forceinline__ ushort f2bf(float f) {
  uint b = __float_as_uint(f);
  b = b + 0x7FFFu + ((b >> 16) & 1u);
  return (ushort)(b >> 16);
}

// ---------- Kernel A: per-channel 9-rectangle maxes -> max_row ----------
__global__ __launch_bounds__(256) void k_chanmax(const float* __restrict__ x,
                                                 float* __restrict__ ws) {
  int c = blockIdx.x, t = threadIdx.x;
  float m[3][3];
#pragma unroll
  for (int i = 0; i < 3; i++)
#pragma unroll
    for (int j = 0; j < 3; j++) m[i][j] = -INFINITY;

  for (int e = t; e < 16 * HW; e += 256) {
    int n = e / HW;
    int rem = e - n * HW;
    int r = rem / W_;
    int s = rem - r * W_;
    float v = x[(size_t)(n * IN_C + c) * HW + rem];
    bool rc[3] = { r <= 54, true, r >= 1 };
    bool sc[3] = { s <= 54, true, s >= 1 };
#pragma unroll
    for (int i = 0; i < 3; i++)
#pragma unroll
      for (int j = 0; j < 3; j++)
        if (rc[i] && sc[j]) m[i][j] = fmaxf(m[i][j], v);
  }
#pragma unroll
  for (int i = 0; i < 3; i++)
#pragma unroll
    for (int j = 0; j < 3; j++)
      for (int o = 32; o; o >>= 1)
        m[i][j] = fmaxf(m[i][j], __shfl_down(m[i][j], o, 64));

  __shared__ float red[4][9];
  int lane = t & 63, wid = t >> 6;
  if (lane == 0) {
#pragma unroll
    for (int i = 0; i < 3; i++)
#pragma unroll
      for (int j = 0; j < 3; j++) red[wid][i * 3 + j] = m[i][j];
  }
  __syncthreads();
  if (t < 9) {
    float v = fmaxf(fmaxf(red[0][t], red[1][t]), fmaxf(red[2][t], red[3][t]));
    int i = t / 3, j = t - i * 3;
    if (i != 1 || j != 1) v = fmaxf(v, 0.0f);  // padding zeros participate
    ws[(size_t)t * IN_C + c] = v;
  }
}

// ---------- Kernel B: query hash ----------
__global__ __launch_bounds__(256) void k_qhash(const float* __restrict__ a,
                                               float* __restrict__ ws) {
  const float* max_row = ws;
  int t = threadIdx.x;
  double sd = 0.0, sq = 0.0;
  for (int d = t; d < D_; d += 256) {
    double v = (double)max_row[d];
    sd += (double)a[d] * v;
    sq += v * v;
  }
  __shared__ double sh[8], sh2[8];
  int lane = t & 63, wid = t >> 6;
  for (int o = 32; o; o >>= 1) {
    sd += __shfl_down(sd, o, 64);
    sq += __shfl_down(sq, o, 64);
  }
  if (lane == 0) { sh[wid] = sd; sh2[wid] = sq; }
  __syncthreads();
  if (t == 0) {
    double td = 0, tq = 0;
    for (int w = 0; w < 4; w++) { td += sh[w]; tq += sh2[w]; }
    double dot = td / sqrt(tq);
    dot += 0.5 * ((double)a[D_] + (double)a[D_ + 1] + (double)a[D_ + 2] +
                  (double)a[D_ + 3] + (double)a[D_ + 4]);
    long long h = (long long)floor(dot);
    ((int*)ws)[2816] = (int)((h % TBL + TBL) % TBL);
  }
}

// ---------- Kernel C: per-kernel-row hash ----------
__global__ __launch_bounds__(256) void k_khash(const float* __restrict__ kern,
                                               const float* __restrict__ a,
                                               float* __restrict__ ws) {
  int o = blockIdx.x, t = threadIdx.x;
  const float* kr = kern + (size_t)o * D_;
  double sd = 0, sn = 0;
  for (int d = t; d < D_; d += 256) {
    double w = (double)kr[d];
    sd += (double)a[d] * w;
    sn += w * w;
  }
  __shared__ double sh[8], sh2[8];
  int lane = t & 63, wid = t >> 6;
  for (int off = 32; off; off >>= 1) {
    sd += __shfl_down(sd, off, 64);
    sn += __shfl_down(sn, off, 64);
  }
  if (lane == 0) { sh[wid] = sd; sh2[wid] = sn; }
  __syncthreads();
  if (t == 0) {
    double td = 0, tn = 0;
    for (int w = 0; w < 4; w++) { td += sh[w]; tn += sh2[w]; }
    double p1 = tn, p2 = p1 * p1, p4 = p2 * p2, p8 = p4 * p4, p16 = p8 * p8;
    td += (double)a[D_] * p1 + (double)a[D_ + 1] * p2 + (double)a[D_ + 2] * p4 +
          (double)a[D_ + 3] * p8 + (double)a[D_ + 4] * p16;
    long long h = (long long)floor(td);
    ((int*)ws)[2304 + o] = (int)((h % TBL + TBL) % TBL);
  }
}

// ---------- Kernel D: mask + compaction + scale + flags ----------
__global__ __launch_bounds__(512) void k_select(float* __restrict__ ws) {
  int t = threadIdx.x;
  int* hashk = (int*)ws + 2304;
  int* qidx = (int*)ws + 2816;
  int* cntp = (int*)ws + 2817;
  float* scalep = ws + 2818;
  int* active = (int*)ws + 2819;
  int* flags = (int*)ws + 3331;
  __shared__ int cnt;
  if (t == 0) cnt = 0;
  active[t] = 0;
  __syncthreads();
  int q = *qidx;
  bool m = (hashk[t] == q);
  if (m) {
    int p = atomicAdd(&cnt, 1);
    active[p] = t;
  }
  __syncthreads();
  int c = cnt;
  flags[t] = (c == 0) ? 1 : (m ? 1 : 0);
  if (c == 0) active[t] = t;  // fallback: all channels, scale 1
  if (t == 0) {
    if (c > 0) { *cntp = c; *scalep = 512.0f / (float)c; }
    else       { *cntp = 512; *scalep = 1.0f; }
  }
}

// ---------- Kernel P: compact + bf16-convert active weight rows ----------
__global__ __launch_bounds__(256) void k_prep(const float* __restrict__ kern,
                                              float* __restrict__ ws) {
  const int* iws = (const int*)ws;
  int cnt = iws[2817];
  const int* active = iws + 2819;
  ushort* Wc = (ushort*)((char*)ws + 16384);
  int s = blockIdx.x, t = threadIdx.x;
  if (s < cnt) {
    int oc = active[s];
    const float* src = kern + (size_t)oc * D_;
    for (int e = t; e < D_; e += 256) Wc[(size_t)s * D_ + e] = f2bf(src[e]);
  } else {
    for (int e = t; e < D_; e += 256) Wc[(size_t)s * D_ + e] = 0;
  }
}

// ---------- Kernel X: fp32 NCHW -> bf16 padded [cg][n][58][58][32] ----------
__global__ __launch_bounds__(256) void k_xprep(const float* __restrict__ x,
                                               float* __restrict__ ws) {
  ushort* xb = (ushort*)((char*)ws + XB_OFF);
  int bx = blockIdx.x;
  int n = bx & 15, yp = bx >> 4;  // grid 16*58
  int t = threadIdx.x;
  const size_t CGS = (size_t)16 * 58 * XB_ROW;
  size_t rb0 = (size_t)(n * 58 + yp) * XB_ROW;  // cg=0 row base (ushorts)
  uint4 z4 = make_uint4(0u, 0u, 0u, 0u);

  if (yp == 0 || yp == 57) {  // border rows: zeros for all channel groups
    for (int e = t; e < 8 * 232; e += 256) {
      int cg = e / 232, k = e - cg * 232;
      *(uint4*)&xb[rb0 + (size_t)cg * CGS + (size_t)k * 8] = z4;
    }
    return;
  }
  // column borders (wp = 0, 57)
  if (t < 64) {
    int cg = t >> 3, r = t & 7;
    int wp = (r >> 2) ? 57 : 0;
    int oct = r & 3;
    *(uint4*)&xb[rb0 + (size_t)cg * CGS + wp * 32 + oct * 8] = z4;
  }
  int y = yp - 1;
  __shared__ float Lf[64 * 57];
  for (int c0 = 0; c0 < 256; c0 += 64) {
    __syncthreads();
    for (int e = t; e < 3584; e += 256) {  // 64 c x 56 w, coalesced in w
      int ci = e / 56, w = e - ci * 56;
      Lf[ci * 57 + w] = x[(size_t)(n * 256 + c0 + ci) * 3136 + y * 56 + w];
    }
    __syncthreads();
    for (int e = t; e < 448; e += 256) {   // 56 w x 2 cg x 4 oct
      int w = e >> 3, cg_l = (e >> 2) & 1, oct = e & 3;
      int cb = cg_l * 32 + oct * 8;
      uint pk[4];
#pragma unroll
      for (int k = 0; k < 4; k++) {
        uint lo = f2bf(Lf[(cb + 2 * k) * 57 + w]);
        uint hi = f2bf(Lf[(cb + 2 * k + 1) * 57 + w]);
        pk[k] = lo | (hi << 16);
      }
      int cg = (c0 >> 5) + cg_l;
      *(uint4*)&xb[rb0 + (size_t)cg * CGS + (w + 1) * 32 + oct * 8] =
          make_uint4(pk[0], pk[1], pk[2], pk[3]);
    }
  }
}

// ---------- Kernel F: bias fill for inactive channels only ----------
__global__ __launch_bounds__(256) void k_biasfill(const float* __restrict__ bias,
                                                  const float* __restrict__ ws,
                                                  float* __restrict__ out) {
  const int* flags = (const int*)ws + 3331;
  const int total4 = 16 * OUT_C * HW / 4;  // 6422528
  int stride = gridDim.x * blockDim.x;
  for (int i = blockIdx.x * blockDim.x + threadIdx.x; i < total4; i += stride) {
    int o = (i / 784) & (OUT_C - 1);
    if (!flags[o]) {
      float b = bias[o];
      ((float4*)out)[i] = make_float4(b, b, b, b);
    }
  }
}

#define XSTRIDE 40   // ushorts per X row (32 used + 8 pad)
#define ASTRIDE 104  // ushorts per A row (96 used + 8 pad)

// ---------- Kernel E2: implicit-GEMM MFMA conv, bf16-pre-staged X ----------
// Block: 128 oc x 224 px. X staged per 32-ch group from the pre-padded bf16
// buffer (branch-free contiguous uint4 copy). A (3 taps) double-buffered:
// global loads issued BEFORE the 84-MFMA compute, ds_writes after -> one
// barrier per kh, Wc latency hidden under MFMA. setprio(1) around MFMA.
// Accumulation order identical to the previous passing kernel.
__global__ __launch_bounds__(256, 2) void k_convx(const float* __restrict__ bias,
                                                  const float* __restrict__ ws,
                                                  float* __restrict__ out) {
  const int* iws = (const int*)ws;
  int cnt = iws[2817];
  int octile = blockIdx.y;
  if (octile * 128 >= cnt) return;
  float sc = ws[2818];
  const int* active = iws + 2819;
  const ushort* Wc = (const ushort*)((const char*)ws + 16384);
  const ushort* xb = (const ushort*)((const char*)ws + XB_OFF);

  int rt = blockIdx.x;          // image rows 4rt..4rt+3
  int n = blockIdx.z;
  int t = threadIdx.x;
  int lane = t & 63, wid = t >> 6;
  int quad = lane >> 4, l16 = lane & 15;
  int ochalf = wid & 1, pxhalf = wid >> 1;

  __shared__ __align__(16) ushort X_lds[348 * XSTRIDE];    // 27840 B
  __shared__ __align__(16) ushort A_lds[2][128 * ASTRIDE]; // 2 x 26624 B

  // per-b px coords and X base addresses (center tap)
  int pbase[7];
#pragma unroll
  for (int b = 0; b < 7; b++) {
    int pxl = pxhalf * 112 + b * 16 + l16;
    int rl = pxl / 56;
    int col = pxl - rl * 56;
    pbase[b] = ((rl + 1) * 58 + (col + 1)) * XSTRIDE;
  }

  // staging identities
  int oc0 = t >> 2;            // 0..63
  int qs = (t & 3) * 8;        // ushort offset within a 32-ch chunk
  const ushort* W0 = Wc + (size_t)(octile * 128 + oc0) * D_ + qs;
  const ushort* W1 = W0 + (size_t)64 * D_;
  const size_t xbase = (size_t)(n * 58 + rt * 4) * XB_ROW;  // 6 contiguous rows
  const size_t CGS = (size_t)16 * 58 * XB_ROW;

  f32x4 acc[4][7];
#pragma unroll
  for (int a = 0; a < 4; a++)
#pragma unroll
    for (int b = 0; b < 7; b++) acc[a][b] = (f32x4){0.f, 0.f, 0.f, 0.f};

  // prologue: stage X(cc=0) + A(kh=0, cc=0)
  {
    const ushort* xs = xb + xbase;
    for (int e = t; e < 1392; e += 256)
      *(uint4*)&X_lds[(e >> 2) * XSTRIDE + (e & 3) * 8] =
          *(const uint4*)(xs + (size_t)e * 8);
#pragma unroll
    for (int tl = 0; tl < 3; tl++) {
      *(uint4*)&A_lds[0][oc0 * ASTRIDE + tl * 32 + qs] = *(const uint4*)(W0 + tl * IN_C);
      *(uint4*)&A_lds[0][(oc0 + 64) * ASTRIDE + tl * 32 + qs] = *(const uint4*)(W1 + tl * IN_C);
    }
  }
  __syncthreads();

  for (int cc = 0; cc < 8; ++cc) {
    int c0 = cc * 32;
    for (int kh = 0; kh < 3; ++kh) {
      int cur = kh & 1;
      uint4 ar[6];
      bool pf = (kh < 2) || (cc < 7);
      int aoff = (kh < 2) ? ((kh + 1) * 3) * IN_C + c0 : (c0 + 32);
      if (pf) {  // issue next A-tile loads BEFORE compute (latency hidden)
#pragma unroll
        for (int tl = 0; tl < 3; tl++) {
          ar[tl]     = *(const uint4*)(W0 + aoff + tl * IN_C);
          ar[3 + tl] = *(const uint4*)(W1 + aoff + tl * IN_C);
        }
      }
      // compute 3 taps of row kh from A_lds[cur] + X_lds
#pragma unroll
      for (int kw = 0; kw < 3; ++kw) {
        int poff = ((kh - 1) * 58 + (kw - 1)) * XSTRIDE + quad * 8;
        bf16x8 af[4];
#pragma unroll
        for (int a = 0; a < 4; a++) {
          union { uint4 u; bf16x8 v; } cv;
          cv.u = *(const uint4*)&A_lds[cur][(ochalf * 64 + a * 16 + l16) * ASTRIDE +
                                            kw * 32 + quad * 8];
          af[a] = cv.v;
        }
        __builtin_amdgcn_s_setprio(1);
#pragma unroll
        for (int b = 0; b < 7; b++) {
          union { uint4 u; bf16x8 v; } cv;
          cv.u = *(const uint4*)&X_lds[pbase[b] + poff];
          bf16x8 xf = cv.v;
#pragma unroll
          for (int a = 0; a < 4; a++)
            acc[a][b] = __builtin_amdgcn_mfma_f32_16x16x32_bf16(af[a], xf,
                                                                acc[a][b], 0, 0, 0);
        }
        __builtin_amdgcn_s_setprio(0);
      }
      if (kh < 2) {
        int nb = cur ^ 1;
#pragma unroll
        for (int tl = 0; tl < 3; tl++) {
          *(uint4*)&A_lds[nb][oc0 * ASTRIDE + tl * 32 + qs] = ar[tl];
          *(uint4*)&A_lds[nb][(oc0 + 64) * ASTRIDE + tl * 32 + qs] = ar[3 + tl];
        }
        __syncthreads();
      } else {
        __syncthreads();  // all reads of X(cc) and A_lds[0] done
        if (cc < 7) {
          const ushort* xs = xb + xbase + (size_t)(cc + 1) * CGS;
          for (int e = t; e < 1392; e += 256)
            *(uint4*)&X_lds[(e >> 2) * XSTRIDE + (e & 3) * 8] =
                *(const uint4*)(xs + (size_t)e * 8);
#pragma unroll
          for (int tl = 0; tl < 3; tl++) {
            *(uint4*)&A_lds[0][oc0 * ASTRIDE + tl * 32 + qs] = ar[tl];
            *(uint4*)&A_lds[0][(oc0 + 64) * ASTRIDE + tl * 32 + qs] = ar[3 + tl];
          }
          __syncthreads();
        }
      }
    }
  }

  // epilogue: C[m=quad*4+r (oc), n=l16 (px)]
  size_t nbase = (size_t)n * OUT_C * HW;
#pragma unroll
  for (int a = 0; a < 4; a++) {
#pragma unroll
    for (int r = 0; r < 4; r++) {
      int slot = octile * 128 + ochalf * 64 + a * 16 + quad * 4 + r;
      if (slot < cnt) {
        int oc = active[slot];
        float bv = bias[oc];
        size_t obase = nbase + (size_t)oc * HW + rt * 224 + pxhalf * 112 + l16;
#pragma unroll
        for (int b = 0; b < 7; b++)
          out[obase + b * 16] = acc[a][b][r] * sc + bv;
      }
    }
  }
}

// ---------- Kernel E (fallback, fp32-staging; used only if ws too small) ----
__global__ __launch_bounds__(256, 2) void k_conv(const float* __restrict__ x,
                                                 const float* __restrict__ bias,
                                                 const float* __restrict__ ws,
                                                 float* __restrict__ out) {
  const int* iws = (const int*)ws;
  int cnt = iws[2817];
  int octile = blockIdx.y;
  if (octile * 128 >= cnt) return;
  float sc = ws[2818];
  const int* active = iws + 2819;
  const ushort* Wc = (const ushort*)((const char*)ws + 16384);

  int rt = blockIdx.x;
  int n = blockIdx.z;
  int t = threadIdx.x;
  int lane = t & 63, wid = t >> 6;
  int quad = lane >> 4, l16 = lane & 15;
  int ochalf = wid & 1, pxhalf = wid >> 1;

  __shared__ __align__(16) ushort X_lds[348 * XSTRIDE];
  __shared__ __align__(16) ushort A_lds[128 * ASTRIDE];

  const float* xin = x + (size_t)n * IN_C * HW;

  int pbase[7];
#pragma unroll
  for (int b = 0; b < 7; b++) {
    int pxl = pxhalf * 112 + b * 16 + l16;
    int rl = pxl / 56;
    int col = pxl - rl * 56;
    pbase[b] = ((rl + 1) * 58 + (col + 1)) * XSTRIDE;
  }

  f32x4 acc[4][7];
#pragma unroll
  for (int a = 0; a < 4; a++)
#pragma unroll
    for (int b = 0; b < 7; b++) acc[a][b] = (f32x4){0.f, 0.f, 0.f, 0.f};

  for (int cc = 0; cc < 8; ++cc) {
    int c0 = cc * 32;
    __syncthreads();
    for (int e = t; e < 1392; e += 256) {
      int q = e / 348;
      int p = e - q * 348;
      int rl = p / 58;
      int cp = p - rl * 58;
      int y = rt * 4 - 1 + rl;
      int xx = cp - 1;
      float vv[8];
      if ((unsigned)y < 56u && (unsigned)xx < 56u) {
        const float* src = xin + (size_t)(c0 + q * 8) * HW + y * W_ + xx;
#pragma unroll
        for (int k = 0; k < 8; k++) vv[k] = src[(size_t)k * HW];
      } else {
#pragma unroll
        for (int k = 0; k < 8; k++) vv[k] = 0.f;
      }
      uint4 pk;
      pk.x = (uint)f2bf(vv[0]) | ((uint)f2bf(vv[1]) << 16);
      pk.y = (uint)f2bf(vv[2]) | ((uint)f2bf(vv[3]) << 16);
      pk.z = (uint)f2bf(vv[4]) | ((uint)f2bf(vv[5]) << 16);
      pk.w = (uint)f2bf(vv[6]) | ((uint)f2bf(vv[7]) << 16);
      *(uint4*)&X_lds[p * XSTRIDE + q * 8] = pk;
    }

    for (int kh = 0; kh < 3; ++kh) {
      __syncthreads();
      for (int e = t; e < 1536; e += 256) {
        int oc = e / 12;
        int seg = e - oc * 12;
        int tl = seg >> 2, q = seg & 3;
        uint4 v = *(const uint4*)(Wc + (size_t)(octile * 128 + oc) * D_ +
                                  (kh * 3 + tl) * IN_C + c0 + q * 8);
        *(uint4*)&A_lds[oc * ASTRIDE + tl * 32 + q * 8] = v;
      }
      __syncthreads();

      int di = kh - 1;
#pragma unroll
      for (int djj = 0; djj < 3; ++djj) {
        int poff = (di * 58 + (djj - 1)) * XSTRIDE + quad * 8;
        bf16x8 bfr[7];
#pragma unroll
        for (int b = 0; b < 7; b++) {
          union { uint4 u; bf16x8 v; } cv;
          cv.u = *(const uint4*)&X_lds[pbase[b] + poff];
          bfr[b] = cv.v;
        }
#pragma unroll
        for (int a = 0; a < 4; a++) {
          union { uint4 u; bf16x8 v; } cv;
          cv.u = *(const uint4*)&A_lds[(ochalf * 64 + a * 16 + l16) * ASTRIDE +
                                       djj * 32 + quad * 8];
          bf16x8 af = cv.v;
#pragma unroll
          for (int b = 0; b < 7; b++)
            acc[a][b] = __builtin_amdgcn_mfma_f32_16x16x32_bf16(af, bfr[b],
                                                                acc[a][b], 0, 0, 0);
        }
      }
    }
  }

  size_t nbase = (size_t)n * OUT_C * HW;
#pragma unroll
  for (int a = 0; a < 4; a++) {
#pragma unroll
    for (int r = 0; r < 4; r++) {
      int slot = octile * 128 + ochalf * 64 + a * 16 + quad * 4 + r;
      if (slot < cnt) {
        int oc = active[slot];
        float bv = bias[oc];
        size_t obase = nbase + (size_t)oc * HW + rt * 224 + pxhalf * 112 + l16;
#pragma unroll
        for (int b = 0; b < 7; b++)
          out[obase + b * 16] = acc[a][b][r] * sc + bv;
      }
    }
  }
}

extern "C" void kernel_launch(void* const* d_in, const int* in_sizes, int n_in,
                              void* d_out, int out_size, void* d_ws, size_t ws_size,
                              hipStream_t stream) {
  const float* x    = (const float*)d_in[0];
  const float* kern = (const float*)d_in[1];
  const float* bias = (const float*)d_in[2];
  const float* a    = (const float*)d_in[3];
  float* out = (float*)d_out;
  float* ws  = (float*)d_ws;

  const size_t need = XB_OFF + (size_t)8 * 16 * 58 * 58 * 32 * 2;  // 29,933,568 B

  k_chanmax<<<dim3(IN_C), dim3(256), 0, stream>>>(x, ws);
  k_qhash<<<dim3(1), dim3(256), 0, stream>>>(a, ws);
  k_khash<<<dim3(OUT_C), dim3(256), 0, stream>>>(kern, a, ws);
  k_select<<<dim3(1), dim3(512), 0, stream>>>(ws);
  k_prep<<<dim3(OUT_C), dim3(256), 0, stream>>>(kern, ws);
  k_biasfill<<<dim3(4096), dim3(256), 0, stream>>>(bias, ws, out);
  if (ws_size >= need) {
    k_xprep<<<dim3(16 * 58), dim3(256), 0, stream>>>(x, ws);
    k_convx<<<dim3(14, 4, 16), dim3(256), 0, stream>>>(bias, ws, out);
  } else {
    k_conv<<<dim3(14, 4, 16), dim3(256), 0, stream>>>(x, bias, ws, out);
  }
}

// Round 2
// 371.436 us; speedup vs baseline: 1.2083x; 1.2083x over previous
//
#include <hip/hip_runtime.h>
#include <math.h>

#define IN_C   256
#define OUT_C  512
#define HW     3136
#define W_     56
#define D_     2304
#define TBL    16

// ws layout (4-byte units):
// [0,2304)      max_row (float)
// [2304,2816)   hashk (int)
// [2816]        qidx (int)
// [2817]        count_eff (int)
// [2818]        scale_mul (float)
// [2819,3331)   active (int)
// [3331,3843)   flags (int, 1 = channel is computed by conv)
// byte 16384+   Wc: bf16 weights, compacted active rows [512][2304]
// byte 2375680+ Xb: bf16 padded NHWC-ish x [cg=8][n=16][yp=58][wp=58][c=32]

#define XB_OFF 2375680ULL
#define XB_ROW 1856            // ushorts per (cg,n,yp) row: 58*32

typedef __attribute__((ext_vector_type(8))) __bf16 bf16x8;
typedef __attribute__((ext_vector_type(4))) float f32x4;

__device__ __forceinline__ ushort f2bf(float f) {
  uint b = __float_as_uint(f);
  b = b + 0x7FFFu + ((b >> 16) & 1u);
  return (ushort)(b >> 16);
}

// ---------- Kernel A: per-channel 9-rectangle maxes -> max_row ----------
__global__ __launch_bounds__(256) void k_chanmax(const float* __restrict__ x,
                                                 float* __restrict__ ws) {
  int c = blockIdx.x, t = threadIdx.x;
  float m[3][3];
#pragma unroll
  for (int i = 0; i < 3; i++)
#pragma unroll
    for (int j = 0; j < 3; j++) m[i][j] = -INFINITY;

  for (int e = t; e < 16 * HW; e += 256) {
    int n = e / HW;
    int rem = e - n * HW;
    int r = rem / W_;
    int s = rem - r * W_;
    float v = x[(size_t)(n * IN_C + c) * HW + rem];
    bool rc[3] = { r <= 54, true, r >= 1 };
    bool sc[3] = { s <= 54, true, s >= 1 };
#pragma unroll
    for (int i = 0; i < 3; i++)
#pragma unroll
      for (int j = 0; j < 3; j++)
        if (rc[i] && sc[j]) m[i][j] = fmaxf(m[i][j], v);
  }
#pragma unroll
  for (int i = 0; i < 3; i++)
#pragma unroll
    for (int j = 0; j < 3; j++)
      for (int o = 32; o; o >>= 1)
        m[i][j] = fmaxf(m[i][j], __shfl_down(m[i][j], o, 64));

  __shared__ float red[4][9];
  int lane = t & 63, wid = t >> 6;
  if (lane == 0) {
#pragma unroll
    for (int i = 0; i < 3; i++)
#pragma unroll
      for (int j = 0; j < 3; j++) red[wid][i * 3 + j] = m[i][j];
  }
  __syncthreads();
  if (t < 9) {
    float v = fmaxf(fmaxf(red[0][t], red[1][t]), fmaxf(red[2][t], red[3][t]));
    int i = t / 3, j = t - i * 3;
    if (i != 1 || j != 1) v = fmaxf(v, 0.0f);  // padding zeros participate
    ws[(size_t)t * IN_C + c] = v;
  }
}

// ---------- Kernel B: query hash ----------
__global__ __launch_bounds__(256) void k_qhash(const float* __restrict__ a,
                                               float* __restrict__ ws) {
  const float* max_row = ws;
  int t = threadIdx.x;
  double sd = 0.0, sq = 0.0;
  for (int d = t; d < D_; d += 256) {
    double v = (double)max_row[d];
    sd += (double)a[d] * v;
    sq += v * v;
  }
  __shared__ double sh[8], sh2[8];
  int lane = t & 63, wid = t >> 6;
  for (int o = 32; o; o >>= 1) {
    sd += __shfl_down(sd, o, 64);
    sq += __shfl_down(sq, o, 64);
  }
  if (lane == 0) { sh[wid] = sd; sh2[wid] = sq; }
  __syncthreads();
  if (t == 0) {
    double td = 0, tq = 0;
    for (int w = 0; w < 4; w++) { td += sh[w]; tq += sh2[w]; }
    double dot = td / sqrt(tq);
    dot += 0.5 * ((double)a[D_] + (double)a[D_ + 1] + (double)a[D_ + 2] +
                  (double)a[D_ + 3] + (double)a[D_ + 4]);
    long long h = (long long)floor(dot);
    ((int*)ws)[2816] = (int)((h % TBL + TBL) % TBL);
  }
}

// ---------- Kernel C: per-kernel-row hash ----------
__global__ __launch_bounds__(256) void k_khash(const float* __restrict__ kern,
                                               const float* __restrict__ a,
                                               float* __restrict__ ws) {
  int o = blockIdx.x, t = threadIdx.x;
  const float* kr = kern + (size_t)o * D_;
  double sd = 0, sn = 0;
  for (int d = t; d < D_; d += 256) {
    double w = (double)kr[d];
    sd += (double)a[d] * w;
    sn += w * w;
  }
  __shared__ double sh[8], sh2[8];
  int lane = t & 63, wid = t >> 6;
  for (int off = 32; off; off >>= 1) {
    sd += __shfl_down(sd, off, 64);
    sn += __shfl_down(sn, off, 64);
  }
  if (lane == 0) { sh[wid] = sd; sh2[wid] = sn; }
  __syncthreads();
  if (t == 0) {
    double td = 0, tn = 0;
    for (int w = 0; w < 4; w++) { td += sh[w]; tn += sh2[w]; }
    double p1 = tn, p2 = p1 * p1, p4 = p2 * p2, p8 = p4 * p4, p16 = p8 * p8;
    td += (double)a[D_] * p1 + (double)a[D_ + 1] * p2 + (double)a[D_ + 2] * p4 +
          (double)a[D_ + 3] * p8 + (double)a[D_ + 4] * p16;
    long long h = (long long)floor(td);
    ((int*)ws)[2304 + o] = (int)((h % TBL + TBL) % TBL);
  }
}

// ---------- Kernel D: mask + compaction + scale + flags ----------
__global__ __launch_bounds__(512) void k_select(float* __restrict__ ws) {
  int t = threadIdx.x;
  int* hashk = (int*)ws + 2304;
  int* qidx = (int*)ws + 2816;
  int* cntp = (int*)ws + 2817;
  float* scalep = ws + 2818;
  int* active = (int*)ws + 2819;
  int* flags = (int*)ws + 3331;
  __shared__ int cnt;
  if (t == 0) cnt = 0;
  active[t] = 0;
  __syncthreads();
  int q = *qidx;
  bool m = (hashk[t] == q);
  if (m) {
    int p = atomicAdd(&cnt, 1);
    active[p] = t;
  }
  __syncthreads();
  int c = cnt;
  flags[t] = (c == 0) ? 1 : (m ? 1 : 0);
  if (c == 0) active[t] = t;  // fallback: all channels, scale 1
  if (t == 0) {
    if (c > 0) { *cntp = c; *scalep = 512.0f / (float)c; }
    else       { *cntp = 512; *scalep = 1.0f; }
  }
}

// ---------- Kernel P: compact + bf16-convert active weight rows ----------
__global__ __launch_bounds__(256) void k_prep(const float* __restrict__ kern,
                                              float* __restrict__ ws) {
  const int* iws = (const int*)ws;
  int cnt = iws[2817];
  const int* active = iws + 2819;
  ushort* Wc = (ushort*)((char*)ws + 16384);
  int s = blockIdx.x, t = threadIdx.x;
  if (s < cnt) {
    int oc = active[s];
    const float* src = kern + (size_t)oc * D_;
    for (int e = t; e < D_; e += 256) Wc[(size_t)s * D_ + e] = f2bf(src[e]);
  } else {
    for (int e = t; e < D_; e += 256) Wc[(size_t)s * D_ + e] = 0;
  }
}

// ---------- Kernel X: fp32 NCHW -> bf16 padded [cg][n][58][58][32] ----------
__global__ __launch_bounds__(256) void k_xprep(const float* __restrict__ x,
                                               float* __restrict__ ws) {
  ushort* xb = (ushort*)((char*)ws + XB_OFF);
  int bx = blockIdx.x;
  int n = bx & 15, yp = bx >> 4;  // grid 16*58
  int t = threadIdx.x;
  const size_t CGS = (size_t)16 * 58 * XB_ROW;
  size_t rb0 = (size_t)(n * 58 + yp) * XB_ROW;  // cg=0 row base (ushorts)
  uint4 z4 = make_uint4(0u, 0u, 0u, 0u);

  if (yp == 0 || yp == 57) {  // border rows: zeros for all channel groups
    for (int e = t; e < 8 * 232; e += 256) {
      int cg = e / 232, k = e - cg * 232;
      *(uint4*)&xb[rb0 + (size_t)cg * CGS + (size_t)k * 8] = z4;
    }
    return;
  }
  // column borders (wp = 0, 57)
  if (t < 64) {
    int cg = t >> 3, r = t & 7;
    int wp = (r >> 2) ? 57 : 0;
    int oct = r & 3;
    *(uint4*)&xb[rb0 + (size_t)cg * CGS + wp * 32 + oct * 8] = z4;
  }
  int y = yp - 1;
  __shared__ float Lf[64 * 57];
  for (int c0 = 0; c0 < 256; c0 += 64) {
    __syncthreads();
    for (int e = t; e < 3584; e += 256) {  // 64 c x 56 w, coalesced in w
      int ci = e / 56, w = e - ci * 56;
      Lf[ci * 57 + w] = x[(size_t)(n * 256 + c0 + ci) * 3136 + y * 56 + w];
    }
    __syncthreads();
    for (int e = t; e < 448; e += 256) {   // 56 w x 2 cg x 4 oct
      int w = e >> 3, cg_l = (e >> 2) & 1, oct = e & 3;
      int cb = cg_l * 32 + oct * 8;
      uint pk[4];
#pragma unroll
      for (int k = 0; k < 4; k++) {
        uint lo = f2bf(Lf[(cb + 2 * k) * 57 + w]);
        uint hi = f2bf(Lf[(cb + 2 * k + 1) * 57 + w]);
        pk[k] = lo | (hi << 16);
      }
      int cg = (c0 >> 5) + cg_l;
      *(uint4*)&xb[rb0 + (size_t)cg * CGS + (w + 1) * 32 + oct * 8] =
          make_uint4(pk[0], pk[1], pk[2], pk[3]);
    }
  }
}

// ---------- Kernel F: bias fill for inactive channels only ----------
__global__ __launch_bounds__(256) void k_biasfill(const float* __restrict__ bias,
                                                  const float* __restrict__ ws,
                                                  float* __restrict__ out) {
  const int* flags = (const int*)ws + 3331;
  const int total4 = 16 * OUT_C * HW / 4;  // 6422528
  int stride = gridDim.x * blockDim.x;
  for (int i = blockIdx.x * blockDim.x + threadIdx.x; i < total4; i += stride) {
    int o = (i / 784) & (OUT_C - 1);
    if (!flags[o]) {
      float b = bias[o];
      ((float4*)out)[i] = make_float4(b, b, b, b);
    }
  }
}

#define XSTR 40      // ushorts per X position row (32 used + 8 pad) -> 5*row+q banks
#define ASTR 40      // ushorts per A row in a tap tile (32 used + 8 pad)
#define XSTRIDE 40   // (fallback kernel)
#define ASTRIDE 104  // (fallback kernel)

// ---------- Kernel E3: 72-phase double-buffered MFMA conv ----------
// Phases = 8 cc-chunks x 9 taps. Per phase: issue tiny A-prefetch (2 uint4/thr)
// and spread X-prefetch (1 uint4/thr, taps 0..5), ds_read frags + 28 MFMA,
// ds_write prefetch to the idle buffers, one barrier. Both A and X double-
// buffered: no intra-phase hazards, loads hide under the MFMA cluster.
// LDS = 2*27840(X) + 2*10240(A) = 76160 B -> 2 blocks/CU. Prefetch footprint
// 12 VGPR -> no spills (round-1 regression). Accumulation order unchanged.
__global__ __launch_bounds__(256, 2) void k_convx(const float* __restrict__ bias,
                                                  const float* __restrict__ ws,
                                                  float* __restrict__ out) {
  const int* iws = (const int*)ws;
  int cnt = iws[2817];
  int octile = blockIdx.y;
  if (octile * 128 >= cnt) return;
  float sc = ws[2818];
  const int* active = iws + 2819;
  const ushort* Wc = (const ushort*)((const char*)ws + 16384);
  const ushort* xb = (const ushort*)((const char*)ws + XB_OFF);

  int rt = blockIdx.x;          // image rows 4rt..4rt+3
  int n = blockIdx.z;
  int t = threadIdx.x;
  int lane = t & 63, wid = t >> 6;
  int quad = lane >> 4, l16 = lane & 15;
  int ochalf = wid & 1, pxhalf = wid >> 1;

  __shared__ __align__(16) ushort X_lds[2][348 * XSTR];  // 2 x 27840 B
  __shared__ __align__(16) ushort A_lds[2][128 * ASTR];  // 2 x 10240 B

  // per-b px coords and X base addresses (center tap)
  int pbase[7];
#pragma unroll
  for (int b = 0; b < 7; b++) {
    int pxl = pxhalf * 112 + b * 16 + l16;
    int rl = pxl / 56;
    int col = pxl - rl * 56;
    pbase[b] = ((rl + 1) * 58 + (col + 1)) * XSTR;
  }

  // A staging identities: thread t handles chunks t and t+256 of 512
  int ar0 = t >> 2;             // row 0..63 (chunk t); chunk t+256 -> row+64
  int aq = (t & 3) * 8;         // ushort offset of 16B chunk within 32-ch row
  const ushort* Wrow0 = Wc + (size_t)(octile * 128 + ar0) * D_ + aq;
  const ushort* Wrow1 = Wrow0 + (size_t)64 * D_;
  int aoff0 = ar0 * ASTR + aq;
  int aoff1 = (ar0 + 64) * ASTR + aq;

  const size_t CGS = (size_t)16 * 58 * XB_ROW;
  const ushort* xsrc = xb + (size_t)(n * 58 + rt * 4) * XB_ROW;  // + cc*CGS

  f32x4 acc[4][7];
#pragma unroll
  for (int a = 0; a < 4; a++)
#pragma unroll
    for (int b = 0; b < 7; b++) acc[a][b] = (f32x4){0.f, 0.f, 0.f, 0.f};

  // prologue: stage A(cc=0,tap=0) and X(cc=0)
  {
    uint4 a0 = *(const uint4*)(Wrow0);
    uint4 a1 = *(const uint4*)(Wrow1);
    *(uint4*)&A_lds[0][aoff0] = a0;
    *(uint4*)&A_lds[0][aoff1] = a1;
    for (int j = t; j < 1392; j += 256)
      *(uint4*)&X_lds[0][(j >> 2) * XSTR + (j & 3) * 8] =
          *(const uint4*)(xsrc + (size_t)j * 8);
  }
  __syncthreads();

  for (int cc = 0; cc < 8; ++cc) {
    const int xc = cc & 1;
#pragma unroll
    for (int tap = 0; tap < 9; ++tap) {
      const int cur = (cc + tap) & 1;
      const bool havenext = !(cc == 7 && tap == 8);
      const int tapn = (tap == 8) ? 0 : tap + 1;
      const int ccn = (tap == 8) ? cc + 1 : cc;
      uint4 a0, a1, xv;
      // issue next-phase A loads (latency hides under MFMAs)
      if (havenext) {
        int goff = tapn * 256 + ccn * 32;
        a0 = *(const uint4*)(Wrow0 + goff);
        a1 = *(const uint4*)(Wrow1 + goff);
      }
      // spread X(cc+1) staging over taps 0..5
      const bool xpf = (tap < 6) && (cc < 7) && (t < 232);
      int xj = tap * 232 + t;
      if (xpf)
        xv = *(const uint4*)(xsrc + (size_t)(cc + 1) * CGS + (size_t)xj * 8);

      // compute this tap (kh,kw compile-time: tap loop is unrolled)
      const int kh = tap / 3, kw = tap - kh * 3;
      const int poff = ((kh - 1) * 58 + (kw - 1)) * XSTR + quad * 8;
      bf16x8 af[4];
#pragma unroll
      for (int a = 0; a < 4; a++) {
        union { uint4 u; bf16x8 v; } cv;
        cv.u = *(const uint4*)&A_lds[cur][(ochalf * 64 + a * 16 + l16) * ASTR +
                                          quad * 8];
        af[a] = cv.v;
      }
      __builtin_amdgcn_s_setprio(1);
#pragma unroll
      for (int b = 0; b < 7; b++) {
        union { uint4 u; bf16x8 v; } cv;
        cv.u = *(const uint4*)&X_lds[xc][pbase[b] + poff];
        bf16x8 xf = cv.v;
#pragma unroll
        for (int a = 0; a < 4; a++)
          acc[a][b] = __builtin_amdgcn_mfma_f32_16x16x32_bf16(af[a], xf,
                                                              acc[a][b], 0, 0, 0);
      }
      __builtin_amdgcn_s_setprio(0);

      // land prefetches in the idle buffers
      if (havenext) {
        const int nxt = cur ^ 1;
        *(uint4*)&A_lds[nxt][aoff0] = a0;
        *(uint4*)&A_lds[nxt][aoff1] = a1;
      }
      if (xpf)
        *(uint4*)&X_lds[xc ^ 1][(xj >> 2) * XSTR + (xj & 3) * 8] = xv;
      __syncthreads();
    }
  }

  // epilogue: C[m=quad*4+r (oc), n=l16 (px)]
  size_t nbase = (size_t)n * OUT_C * HW;
#pragma unroll
  for (int a = 0; a < 4; a++) {
#pragma unroll
    for (int r = 0; r < 4; r++) {
      int slot = octile * 128 + ochalf * 64 + a * 16 + quad * 4 + r;
      if (slot < cnt) {
        int oc = active[slot];
        float bv = bias[oc];
        size_t obase = nbase + (size_t)oc * HW + rt * 224 + pxhalf * 112 + l16;
#pragma unroll
        for (int b = 0; b < 7; b++)
          out[obase + b * 16] = acc[a][b][r] * sc + bv;
      }
    }
  }
}

// ---------- Kernel E (fallback, fp32-staging; used only if ws too small) ----
__global__ __launch_bounds__(256, 2) void k_conv(const float* __restrict__ x,
                                                 const float* __restrict__ bias,
                                                 const float* __restrict__ ws,
                                                 float* __restrict__ out) {
  const int* iws = (const int*)ws;
  int cnt = iws[2817];
  int octile = blockIdx.y;
  if (octile * 128 >= cnt) return;
  float sc = ws[2818];
  const int* active = iws + 2819;
  const ushort* Wc = (const ushort*)((const char*)ws + 16384);

  int rt = blockIdx.x;
  int n = blockIdx.z;
  int t = threadIdx.x;
  int lane = t & 63, wid = t >> 6;
  int quad = lane >> 4, l16 = lane & 15;
  int ochalf = wid & 1, pxhalf = wid >> 1;

  __shared__ __align__(16) ushort X_lds[348 * XSTRIDE];
  __shared__ __align__(16) ushort A_lds[128 * ASTRIDE];

  const float* xin = x + (size_t)n * IN_C * HW;

  int pbase[7];
#pragma unroll
  for (int b = 0; b < 7; b++) {
    int pxl = pxhalf * 112 + b * 16 + l16;
    int rl = pxl / 56;
    int col = pxl - rl * 56;
    pbase[b] = ((rl + 1) * 58 + (col + 1)) * XSTRIDE;
  }

  f32x4 acc[4][7];
#pragma unroll
  for (int a = 0; a < 4; a++)
#pragma unroll
    for (int b = 0; b < 7; b++) acc[a][b] = (f32x4){0.f, 0.f, 0.f, 0.f};

  for (int cc = 0; cc < 8; ++cc) {
    int c0 = cc * 32;
    __syncthreads();
    for (int e = t; e < 1392; e += 256) {
      int q = e / 348;
      int p = e - q * 348;
      int rl = p / 58;
      int cp = p - rl * 58;
      int y = rt * 4 - 1 + rl;
      int xx = cp - 1;
      float vv[8];
      if ((unsigned)y < 56u && (unsigned)xx < 56u) {
        const float* src = xin + (size_t)(c0 + q * 8) * HW + y * W_ + xx;
#pragma unroll
        for (int k = 0; k < 8; k++) vv[k] = src[(size_t)k * HW];
      } else {
#pragma unroll
        for (int k = 0; k < 8; k++) vv[k] = 0.f;
      }
      uint4 pk;
      pk.x = (uint)f2bf(vv[0]) | ((uint)f2bf(vv[1]) << 16);
      pk.y = (uint)f2bf(vv[2]) | ((uint)f2bf(vv[3]) << 16);
      pk.z = (uint)f2bf(vv[4]) | ((uint)f2bf(vv[5]) << 16);
      pk.w = (uint)f2bf(vv[6]) | ((uint)f2bf(vv[7]) << 16);
      *(uint4*)&X_lds[p * XSTRIDE + q * 8] = pk;
    }

    for (int kh = 0; kh < 3; ++kh) {
      __syncthreads();
      for (int e = t; e < 1536; e += 256) {
        int oc = e / 12;
        int seg = e - oc * 12;
        int tl = seg >> 2, q = seg & 3;
        uint4 v = *(const uint4*)(Wc + (size_t)(octile * 128 + oc) * D_ +
                                  (kh * 3 + tl) * IN_C + c0 + q * 8);
        *(uint4*)&A_lds[oc * ASTRIDE + tl * 32 + q * 8] = v;
      }
      __syncthreads();

      int di = kh - 1;
#pragma unroll
      for (int djj = 0; djj < 3; ++djj) {
        int poff = (di * 58 + (djj - 1)) * XSTRIDE + quad * 8;
        bf16x8 bfr[7];
#pragma unroll
        for (int b = 0; b < 7; b++) {
          union { uint4 u; bf16x8 v; } cv;
          cv.u = *(const uint4*)&X_lds[pbase[b] + poff];
          bfr[b] = cv.v;
        }
#pragma unroll
        for (int a = 0; a < 4; a++) {
          union { uint4 u; bf16x8 v; } cv;
          cv.u = *(const uint4*)&A_lds[(ochalf * 64 + a * 16 + l16) * ASTRIDE +
                                       djj * 32 + quad * 8];
          bf16x8 af = cv.v;
#pragma unroll
          for (int b = 0; b < 7; b++)
            acc[a][b] = __builtin_amdgcn_mfma_f32_16x16x32_bf16(af, bfr[b],
                                                                acc[a][b], 0, 0, 0);
        }
      }
    }
  }

  size_t nbase = (size_t)n * OUT_C * HW;
#pragma unroll
  for (int a = 0; a < 4; a++) {
#pragma unroll
    for (int r = 0; r < 4; r++) {
      int slot = octile * 128 + ochalf * 64 + a * 16 + quad * 4 + r;
      if (slot < cnt) {
        int oc = active[slot];
        float bv = bias[oc];
        size_t obase = nbase + (size_t)oc * HW + rt * 224 + pxhalf * 112 + l16;
#pragma unroll
        for (int b = 0; b < 7; b++)
          out[obase + b * 16] = acc[a][b][r] * sc + bv;
      }
    }
  }
}

extern "C" void kernel_launch(void* const* d_in, const int* in_sizes, int n_in,
                              void* d_out, int out_size, void* d_ws, size_t ws_size,
                              hipStream_t stream) {
  const float* x    = (const float*)d_in[0];
  const float* kern = (const float*)d_in[1];
  const float* bias = (const float*)d_in[2];
  const float* a    = (const float*)d_in[3];
  float* out = (float*)d_out;
  float* ws  = (float*)d_ws;

  const size_t need = XB_OFF + (size_t)8 * 16 * 58 * 58 * 32 * 2;  // 29,933,568 B

  k_chanmax<<<dim3(IN_C), dim3(256), 0, stream>>>(x, ws);
  k_qhash<<<dim3(1), dim3(256), 0, stream>>>(a, ws);
  k_khash<<<dim3(OUT_C), dim3(256), 0, stream>>>(kern, a, ws);
  k_select<<<dim3(1), dim3(512), 0, stream>>>(ws);
  k_prep<<<dim3(OUT_C), dim3(256), 0, stream>>>(kern, ws);
  k_biasfill<<<dim3(4096), dim3(256), 0, stream>>>(bias, ws, out);
  if (ws_size >= need) {
    k_xprep<<<dim3(16 * 58), dim3(256), 0, stream>>>(x, ws);
    k_convx<<<dim3(14, 4, 16), dim3(256), 0, stream>>>(bias, ws, out);
  } else {
    k_conv<<<dim3(14, 4, 16), dim3(256), 0, stream>>>(x, bias, ws, out);
  }
}

// Round 3
// 298.649 us; speedup vs baseline: 1.5027x; 1.2437x over previous
//
#include <hip/hip_runtime.h>
#include <math.h>

#define IN_C   256
#define OUT_C  512
#define HW     3136
#define W_     56
#define D_     2304
#define TBL    16

// ws layout (4-byte units):
// [0,2304)      max_row (float)           (fallback path only)
// [2304,2816)   hashk (int)
// [2816]        qidx (int)
// [2817]        count_eff (int)
// [2818]        scale_mul (float)
// [2819,3331)   active (int)
// [3331,3843)   inact (int, fast path) / flags (fallback)
// byte 16384+   Wc: bf16 weights, compacted active rows [512][2304]
// byte 2375680+ Xb: bf16 padded x [cg=8][n=16][yp=58][wp=58][c=32]
// byte 29933568+ P: chanmax partials [part=4][tap=9][c=256] float (fast path)

#define XB_OFF 2375680ULL
#define XB_ROW 1856            // ushorts per (cg,n,yp) row: 58*32
#define P_OFF  7483392         // float index of partials (byte 29933568)

typedef __attribute__((ext_vector_type(8))) __bf16 bf16x8;
typedef __attribute__((ext_vector_type(4))) float f32x4;

__device__ __forceinline__ ushort f2bf(float f) {
  uint b = __float_as_uint(f);
  b = b + 0x7FFFu + ((b >> 16) & 1u);
  return (ushort)(b >> 16);
}

// ================= FAST PATH =================

// ---------- Kernel S: fused setup — xprep(3712) + chanmax-part(1024) + khash(512)
__global__ __launch_bounds__(256) void k_setup(const float* __restrict__ x,
                                               const float* __restrict__ kern,
                                               const float* __restrict__ a,
                                               float* __restrict__ ws) {
  __shared__ __align__(16) float smem[64 * 57];  // 14592 B, aliased per path
  int bx = blockIdx.x, t = threadIdx.x;

  if (bx < 3712) {
    // ---- xprep: fp32 NCHW -> bf16 padded [cg][n][58][58][32], one 64-ch chunk ----
    int c0i = bx & 3;             // 64-channel chunk
    int n = (bx >> 2) & 15;
    int yp = bx >> 6;             // 0..57
    int c0 = c0i * 64, cgbase = c0i * 2;
    ushort* xb = (ushort*)((char*)ws + XB_OFF);
    const size_t CGS = (size_t)16 * 58 * XB_ROW;
    size_t rb0 = (size_t)(n * 58 + yp) * XB_ROW;
    uint4 z4 = make_uint4(0u, 0u, 0u, 0u);

    if (yp == 0 || yp == 57) {    // border rows: zeros for this block's 2 cgs
      for (int e = t; e < 464; e += 256) {
        int cg_l = e / 232, k = e - cg_l * 232;
        *(uint4*)&xb[rb0 + (size_t)(cgbase + cg_l) * CGS + (size_t)k * 8] = z4;
      }
      return;
    }
    if (t < 16) {                 // column borders wp = 0, 57
      int cg_l = t >> 3, r = t & 7;
      int wp = (r >> 2) ? 57 : 0, oct = r & 3;
      *(uint4*)&xb[rb0 + (size_t)(cgbase + cg_l) * CGS + wp * 32 + oct * 8] = z4;
    }
    int y = yp - 1;
    float* Lf = smem;             // [64][57]
    for (int e = t; e < 3584; e += 256) {
      int ci = e / 56, w = e - ci * 56;
      Lf[ci * 57 + w] = x[(size_t)(n * 256 + c0 + ci) * 3136 + y * 56 + w];
    }
    __syncthreads();
    for (int e = t; e < 448; e += 256) {
      int w = e >> 3, cg_l = (e >> 2) & 1, oct = e & 3;
      int cb = cg_l * 32 + oct * 8;
      uint pk[4];
#pragma unroll
      for (int k = 0; k < 4; k++) {
        uint lo = f2bf(Lf[(cb + 2 * k) * 57 + w]);
        uint hi = f2bf(Lf[(cb + 2 * k + 1) * 57 + w]);
        pk[k] = lo | (hi << 16);
      }
      *(uint4*)&xb[rb0 + (size_t)(cgbase + cg_l) * CGS + (w + 1) * 32 + oct * 8] =
          make_uint4(pk[0], pk[1], pk[2], pk[3]);
    }
  } else if (bx < 4736) {
    // ---- chanmax partial: 4 blocks/channel, 4 images each ----
    int idx = bx - 3712;
    int c = idx & 255, part = idx >> 8;
    float m[3][3];
#pragma unroll
    for (int i = 0; i < 3; i++)
#pragma unroll
      for (int j = 0; j < 3; j++) m[i][j] = -INFINITY;
    for (int e = t; e < 4 * HW; e += 256) {
      int nl = e / HW;
      int rem = e - nl * HW;
      int r = rem / W_;
      int s = rem - r * W_;
      float v = x[(size_t)((part * 4 + nl) * IN_C + c) * HW + rem];
      bool rc[3] = { r <= 54, true, r >= 1 };
      bool sc[3] = { s <= 54, true, s >= 1 };
#pragma unroll
      for (int i = 0; i < 3; i++)
#pragma unroll
        for (int j = 0; j < 3; j++)
          if (rc[i] && sc[j]) m[i][j] = fmaxf(m[i][j], v);
    }
#pragma unroll
    for (int i = 0; i < 3; i++)
#pragma unroll
      for (int j = 0; j < 3; j++)
        for (int o = 32; o; o >>= 1)
          m[i][j] = fmaxf(m[i][j], __shfl_down(m[i][j], o, 64));
    float* red = smem;            // [4][9]
    int lane = t & 63, wid = t >> 6;
    if (lane == 0) {
#pragma unroll
      for (int i = 0; i < 3; i++)
#pragma unroll
        for (int j = 0; j < 3; j++) red[wid * 9 + i * 3 + j] = m[i][j];
    }
    __syncthreads();
    if (t < 9) {
      float v = fmaxf(fmaxf(red[0 * 9 + t], red[1 * 9 + t]),
                      fmaxf(red[2 * 9 + t], red[3 * 9 + t]));
      ws[P_OFF + (size_t)part * 2304 + (size_t)t * IN_C + c] = v;  // no 0-cap here
    }
  } else {
    // ---- khash: per-kernel-row hash ----
    int o = bx - 4736;
    const float* kr = kern + (size_t)o * D_;
    double sd = 0, sn = 0;
    for (int d = t; d < D_; d += 256) {
      double w = (double)kr[d];
      sd += (double)a[d] * w;
      sn += w * w;
    }
    double* sh = (double*)smem;
    double* sh2 = sh + 8;
    int lane = t & 63, wid = t >> 6;
    for (int off = 32; off; off >>= 1) {
      sd += __shfl_down(sd, off, 64);
      sn += __shfl_down(sn, off, 64);
    }
    if (lane == 0) { sh[wid] = sd; sh2[wid] = sn; }
    __syncthreads();
    if (t == 0) {
      double td = 0, tn = 0;
      for (int w = 0; w < 4; w++) { td += sh[w]; tn += sh2[w]; }
      double p1 = tn, p2 = p1 * p1, p4 = p2 * p2, p8 = p4 * p4, p16 = p8 * p8;
      td += (double)a[D_] * p1 + (double)a[D_ + 1] * p2 + (double)a[D_ + 2] * p4 +
            (double)a[D_ + 3] * p8 + (double)a[D_ + 4] * p16;
      long long h = (long long)floor(td);
      ((int*)ws)[2304 + o] = (int)((h % TBL + TBL) % TBL);
    }
  }
}

// ---------- Kernel R: qhash (reduce partials) + select, one block ----------
__global__ __launch_bounds__(512) void k_route(const float* __restrict__ a,
                                               float* __restrict__ ws) {
  int t = threadIdx.x;
  const float* P = ws + P_OFF;
  __shared__ double sh[8], sh2[8];
  __shared__ int shq, c1, c2;
  double sd = 0.0, sq = 0.0;
  if (t < 256) {  // identical summation order to the old 256-thread k_qhash
    for (int d = t; d < D_; d += 256) {
      float v = fmaxf(fmaxf(P[d], P[2304 + d]), fmaxf(P[4608 + d], P[6912 + d]));
      if ((d >> 8) != 4) v = fmaxf(v, 0.0f);  // padding zeros, non-center taps
      double dv = (double)v;
      sd += (double)a[d] * dv;
      sq += dv * dv;
    }
    for (int o = 32; o; o >>= 1) {
      sd += __shfl_down(sd, o, 64);
      sq += __shfl_down(sq, o, 64);
    }
    if ((t & 63) == 0) { sh[t >> 6] = sd; sh2[t >> 6] = sq; }
  }
  __syncthreads();
  if (t == 0) {
    double td = 0, tq = 0;
    for (int w = 0; w < 4; w++) { td += sh[w]; tq += sh2[w]; }
    double dot = td / sqrt(tq);
    dot += 0.5 * ((double)a[D_] + (double)a[D_ + 1] + (double)a[D_ + 2] +
                  (double)a[D_ + 3] + (double)a[D_ + 4]);
    long long h = (long long)floor(dot);
    int q = (int)((h % TBL + TBL) % TBL);
    ((int*)ws)[2816] = q;
    shq = q;
    c1 = 0; c2 = 0;
  }
  __syncthreads();
  // ---- select: active + inactive lists ----
  int* hashk = (int*)ws + 2304;
  int* cntp = (int*)ws + 2817;
  float* scalep = ws + 2818;
  int* active = (int*)ws + 2819;
  int* inact = (int*)ws + 3331;
  int q = shq;
  bool m = (hashk[t] == q);
  if (m) active[atomicAdd(&c1, 1)] = t;
  else   inact[atomicAdd(&c2, 1)] = t;
  __syncthreads();
  int c = c1;
  if (c == 0) active[t] = t;  // fallback: all channels, scale 1
  if (t == 0) {
    if (c > 0) { *cntp = c; *scalep = 512.0f / (float)c; }
    else       { *cntp = 512; *scalep = 1.0f; }
  }
}

// ---------- Kernel P: compact + bf16-convert active weight rows ----------
__global__ __launch_bounds__(256) void k_prep(const float* __restrict__ kern,
                                              float* __restrict__ ws) {
  const int* iws = (const int*)ws;
  int cnt = iws[2817];
  const int* active = iws + 2819;
  uint* Wc = (uint*)((char*)ws + 16384);
  int s = blockIdx.x, t = threadIdx.x;
  if (s < cnt) {
    int oc = active[s];
    const float* src = kern + (size_t)oc * D_;
    for (int e = t; e < 1152; e += 256) {
      uint lo = f2bf(src[2 * e]);
      uint hi = f2bf(src[2 * e + 1]);
      Wc[(size_t)s * 1152 + e] = lo | (hi << 16);
    }
  } else {
    for (int e = t; e < 1152; e += 256) Wc[(size_t)s * 1152 + e] = 0;
  }
}

#define XSTR 40      // ushorts per X position row (32 used + 8 pad)
#define ASTR 40      // ushorts per A row in a tap tile (32 used + 8 pad)
#define XSTRIDE 40   // (fallback kernel)
#define ASTRIDE 104  // (fallback kernel)

// ---------- Kernel E4: 72-phase conv, 2-deep A prefetch + fused bias fill ----
// Per phase: issue A(g+2) loads (regs), issue X(cc+1) part (reg), MFMA from
// LDS, land A(g+1) regs (loaded 2 phases ago -> vmcnt satisfied, no stall),
// land X part held one phase, one barrier. Inactive slots (>= cnt) get bias
// written by the same grid (k_biasfill eliminated). Accumulation order
// identical to round-2 kernel.
__global__ __launch_bounds__(256, 2) void k_convx(const float* __restrict__ bias,
                                                  const float* __restrict__ ws,
                                                  float* __restrict__ out) {
  const int* iws = (const int*)ws;
  int cnt = iws[2817];
  int octile = blockIdx.y;
  int rt = blockIdx.x;          // image rows 4rt..4rt+3
  int n = blockIdx.z;
  int t = threadIdx.x;

  // ---- bias fill for this block's inactive slots (none when cnt==512) ----
  {
    int base = octile * 128;
    int lo = base < cnt ? cnt : base;
    int hi = base + 128;
    if (lo < hi) {
      const int* inact = iws + 3331;
      size_t nbase = (size_t)n * OUT_C * HW;
      int nin = hi - lo;
      for (int e = t; e < nin * 56; e += 256) {
        int j = e / 56, f = e - j * 56;
        int oc = inact[lo - cnt + j];
        float bv = bias[oc];
        ((float4*)out)[(nbase + (size_t)oc * HW + rt * 224) / 4 + f] =
            make_float4(bv, bv, bv, bv);
      }
    }
    if (base >= cnt) return;
  }

  float sc = ws[2818];
  const int* active = iws + 2819;
  const ushort* Wc = (const ushort*)((const char*)ws + 16384);
  const ushort* xb = (const ushort*)((const char*)ws + XB_OFF);

  int lane = t & 63, wid = t >> 6;
  int quad = lane >> 4, l16 = lane & 15;
  int ochalf = wid & 1, pxhalf = wid >> 1;

  __shared__ __align__(16) ushort X_lds[2][348 * XSTR];  // 2 x 27840 B
  __shared__ __align__(16) ushort A_lds[2][128 * ASTR];  // 2 x 10240 B

  int pbase[7];
#pragma unroll
  for (int b = 0; b < 7; b++) {
    int pxl = pxhalf * 112 + b * 16 + l16;
    int rl = pxl / 56;
    int col = pxl - rl * 56;
    pbase[b] = ((rl + 1) * 58 + (col + 1)) * XSTR;
  }

  int ar0 = t >> 2;             // A staging row 0..63 (and +64)
  int aq = (t & 3) * 8;
  const ushort* Wrow0 = Wc + (size_t)(octile * 128 + ar0) * D_ + aq;
  const ushort* Wrow1 = Wrow0 + (size_t)64 * D_;
  int aoff0 = ar0 * ASTR + aq;
  int aoff1 = (ar0 + 64) * ASTR + aq;

  const size_t CGS = (size_t)16 * 58 * XB_ROW;
  const ushort* xsrc = xb + (size_t)(n * 58 + rt * 4) * XB_ROW;

  f32x4 acc[4][7];
#pragma unroll
  for (int a = 0; a < 4; a++)
#pragma unroll
    for (int b = 0; b < 7; b++) acc[a][b] = (f32x4){0.f, 0.f, 0.f, 0.f};

  uint4 pA0, pA1, nA0, nA1;     // A regs: phase g+1 (p) and g+2 (n)
  uint4 xh; int xhj = 0; bool xhv = false;

  // prologue: A(g=0)->LDS, X(cc=0)->LDS, issue A(g=1)->regs
  {
    uint4 a0 = *(const uint4*)(Wrow0);
    uint4 a1 = *(const uint4*)(Wrow1);
    *(uint4*)&A_lds[0][aoff0] = a0;
    *(uint4*)&A_lds[0][aoff1] = a1;
    for (int j = t; j < 1392; j += 256)
      *(uint4*)&X_lds[0][(j >> 2) * XSTR + (j & 3) * 8] =
          *(const uint4*)(xsrc + (size_t)j * 8);
    pA0 = *(const uint4*)(Wrow0 + 256);   // g=1: tap=1, cc=0
    pA1 = *(const uint4*)(Wrow1 + 256);
  }
  __syncthreads();

  for (int cc = 0; cc < 8; ++cc) {
    const int xc = cc & 1;
#pragma unroll
    for (int tap = 0; tap < 9; ++tap) {
      const int cur = (cc + tap) & 1;      // phase parity (9 odd -> continuous)
      const bool last = (cc == 7) && (tap == 8);
      // issue A(g+2)
      const int tap2 = (tap + 2) % 9;      // compile-time
      const int cc2 = cc + (tap + 2) / 9;  // runtime
      if (cc2 < 8) {
        int goff = tap2 * 256 + cc2 * 32;
        nA0 = *(const uint4*)(Wrow0 + goff);
        nA1 = *(const uint4*)(Wrow1 + goff);
      }
      // issue X(cc+1) part 'tap' (landed next phase)
      const bool xpf = (tap < 6) && (cc < 7) && (t < 232);
      uint4 xv; int xj = tap * 232 + t;
      if (xpf)
        xv = *(const uint4*)(xsrc + (size_t)(cc + 1) * CGS + (size_t)xj * 8);

      // ---- 28 MFMAs from A_lds[cur], X_lds[xc] ----
      const int kh = tap / 3, kw = tap - kh * 3;
      const int poff = ((kh - 1) * 58 + (kw - 1)) * XSTR + quad * 8;
      bf16x8 af[4];
#pragma unroll
      for (int a = 0; a < 4; a++) {
        union { uint4 u; bf16x8 v; } cv;
        cv.u = *(const uint4*)&A_lds[cur][(ochalf * 64 + a * 16 + l16) * ASTR +
                                          quad * 8];
        af[a] = cv.v;
      }
      __builtin_amdgcn_s_setprio(1);
#pragma unroll
      for (int b = 0; b < 7; b++) {
        union { uint4 u; bf16x8 v; } cv;
        cv.u = *(const uint4*)&X_lds[xc][pbase[b] + poff];
        bf16x8 xf = cv.v;
#pragma unroll
        for (int a = 0; a < 4; a++)
          acc[a][b] = __builtin_amdgcn_mfma_f32_16x16x32_bf16(af[a], xf,
                                                              acc[a][b], 0, 0, 0);
      }
      __builtin_amdgcn_s_setprio(0);

      // land A(g+1): loaded 2 phases ago -> no vmcnt stall
      if (!last) {
        *(uint4*)&A_lds[cur ^ 1][aoff0] = pA0;
        *(uint4*)&A_lds[cur ^ 1][aoff1] = pA1;
      }
      // land X part held from previous phase
      if (xhv)
        *(uint4*)&X_lds[xc ^ 1][(xhj >> 2) * XSTR + (xhj & 3) * 8] = xh;
      __syncthreads();
      pA0 = nA0; pA1 = nA1;
      xh = xv; xhj = xj; xhv = xpf;
    }
  }

  // epilogue: C[m=quad*4+r (oc), n=l16 (px)]
  size_t nbase = (size_t)n * OUT_C * HW;
#pragma unroll
  for (int a = 0; a < 4; a++) {
#pragma unroll
    for (int r = 0; r < 4; r++) {
      int slot = octile * 128 + ochalf * 64 + a * 16 + quad * 4 + r;
      if (slot < cnt) {
        int oc = active[slot];
        float bv = bias[oc];
        size_t obase = nbase + (size_t)oc * HW + rt * 224 + pxhalf * 112 + l16;
#pragma unroll
        for (int b = 0; b < 7; b++)
          out[obase + b * 16] = acc[a][b][r] * sc + bv;
      }
    }
  }
}

// ================= FALLBACK PATH (ws too small) =================

__global__ __launch_bounds__(256) void k_chanmax(const float* __restrict__ x,
                                                 float* __restrict__ ws) {
  int c = blockIdx.x, t = threadIdx.x;
  float m[3][3];
#pragma unroll
  for (int i = 0; i < 3; i++)
#pragma unroll
    for (int j = 0; j < 3; j++) m[i][j] = -INFINITY;
  for (int e = t; e < 16 * HW; e += 256) {
    int n = e / HW;
    int rem = e - n * HW;
    int r = rem / W_;
    int s = rem - r * W_;
    float v = x[(size_t)(n * IN_C + c) * HW + rem];
    bool rc[3] = { r <= 54, true, r >= 1 };
    bool sc[3] = { s <= 54, true, s >= 1 };
#pragma unroll
    for (int i = 0; i < 3; i++)
#pragma unroll
      for (int j = 0; j < 3; j++)
        if (rc[i] && sc[j]) m[i][j] = fmaxf(m[i][j], v);
  }
#pragma unroll
  for (int i = 0; i < 3; i++)
#pragma unroll
    for (int j = 0; j < 3; j++)
      for (int o = 32; o; o >>= 1)
        m[i][j] = fmaxf(m[i][j], __shfl_down(m[i][j], o, 64));
  __shared__ float red[4][9];
  int lane = t & 63, wid = t >> 6;
  if (lane == 0) {
#pragma unroll
    for (int i = 0; i < 3; i++)
#pragma unroll
      for (int j = 0; j < 3; j++) red[wid][i * 3 + j] = m[i][j];
  }
  __syncthreads();
  if (t < 9) {
    float v = fmaxf(fmaxf(red[0][t], red[1][t]), fmaxf(red[2][t], red[3][t]));
    int i = t / 3, j = t - i * 3;
    if (i != 1 || j != 1) v = fmaxf(v, 0.0f);
    ws[(size_t)t * IN_C + c] = v;
  }
}

__global__ __launch_bounds__(256) void k_qhash(const float* __restrict__ a,
                                               float* __restrict__ ws) {
  const float* max_row = ws;
  int t = threadIdx.x;
  double sd = 0.0, sq = 0.0;
  for (int d = t; d < D_; d += 256) {
    double v = (double)max_row[d];
    sd += (double)a[d] * v;
    sq += v * v;
  }
  __shared__ double sh[8], sh2[8];
  int lane = t & 63, wid = t >> 6;
  for (int o = 32; o; o >>= 1) {
    sd += __shfl_down(sd, o, 64);
    sq += __shfl_down(sq, o, 64);
  }
  if (lane == 0) { sh[wid] = sd; sh2[wid] = sq; }
  __syncthreads();
  if (t == 0) {
    double td = 0, tq = 0;
    for (int w = 0; w < 4; w++) { td += sh[w]; tq += sh2[w]; }
    double dot = td / sqrt(tq);
    dot += 0.5 * ((double)a[D_] + (double)a[D_ + 1] + (double)a[D_ + 2] +
                  (double)a[D_ + 3] + (double)a[D_ + 4]);
    long long h = (long long)floor(dot);
    ((int*)ws)[2816] = (int)((h % TBL + TBL) % TBL);
  }
}

__global__ __launch_bounds__(256) void k_khash(const float* __restrict__ kern,
                                               const float* __restrict__ a,
                                               float* __restrict__ ws) {
  int o = blockIdx.x, t = threadIdx.x;
  const float* kr = kern + (size_t)o * D_;
  double sd = 0, sn = 0;
  for (int d = t; d < D_; d += 256) {
    double w = (double)kr[d];
    sd += (double)a[d] * w;
    sn += w * w;
  }
  __shared__ double sh[8], sh2[8];
  int lane = t & 63, wid = t >> 6;
  for (int off = 32; off; off >>= 1) {
    sd += __shfl_down(sd, off, 64);
    sn += __shfl_down(sn, off, 64);
  }
  if (lane == 0) { sh[wid] = sd; sh2[wid] = sn; }
  __syncthreads();
  if (t == 0) {
    double td = 0, tn = 0;
    for (int w = 0; w < 4; w++) { td += sh[w]; tn += sh2[w]; }
    double p1 = tn, p2 = p1 * p1, p4 = p2 * p2, p8 = p4 * p4, p16 = p8 * p8;
    td += (double)a[D_] * p1 + (double)a[D_ + 1] * p2 + (double)a[D_ + 2] * p4 +
          (double)a[D_ + 3] * p8 + (double)a[D_ + 4] * p16;
    long long h = (long long)floor(td);
    ((int*)ws)[2304 + o] = (int)((h % TBL + TBL) % TBL);
  }
}

__global__ __launch_bounds__(512) void k_select(float* __restrict__ ws) {
  int t = threadIdx.x;
  int* hashk = (int*)ws + 2304;
  int* qidx = (int*)ws + 2816;
  int* cntp = (int*)ws + 2817;
  float* scalep = ws + 2818;
  int* active = (int*)ws + 2819;
  int* flags = (int*)ws + 3331;
  __shared__ int cnt;
  if (t == 0) cnt = 0;
  active[t] = 0;
  __syncthreads();
  int q = *qidx;
  bool m = (hashk[t] == q);
  if (m) {
    int p = atomicAdd(&cnt, 1);
    active[p] = t;
  }
  __syncthreads();
  int c = cnt;
  flags[t] = (c == 0) ? 1 : (m ? 1 : 0);
  if (c == 0) active[t] = t;
  if (t == 0) {
    if (c > 0) { *cntp = c; *scalep = 512.0f / (float)c; }
    else       { *cntp = 512; *scalep = 1.0f; }
  }
}

__global__ __launch_bounds__(256) void k_biasfill(const float* __restrict__ bias,
                                                  const float* __restrict__ ws,
                                                  float* __restrict__ out) {
  const int* flags = (const int*)ws + 3331;
  const int total4 = 16 * OUT_C * HW / 4;
  int stride = gridDim.x * blockDim.x;
  for (int i = blockIdx.x * blockDim.x + threadIdx.x; i < total4; i += stride) {
    int o = (i / 784) & (OUT_C - 1);
    if (!flags[o]) {
      float b = bias[o];
      ((float4*)out)[i] = make_float4(b, b, b, b);
    }
  }
}

__global__ __launch_bounds__(256, 2) void k_conv(const float* __restrict__ x,
                                                 const float* __restrict__ bias,
                                                 const float* __restrict__ ws,
                                                 float* __restrict__ out) {
  const int* iws = (const int*)ws;
  int cnt = iws[2817];
  int octile = blockIdx.y;
  if (octile * 128 >= cnt) return;
  float sc = ws[2818];
  const int* active = iws + 2819;
  const ushort* Wc = (const ushort*)((const char*)ws + 16384);
  int rt = blockIdx.x;
  int n = blockIdx.z;
  int t = threadIdx.x;
  int lane = t & 63, wid = t >> 6;
  int quad = lane >> 4, l16 = lane & 15;
  int ochalf = wid & 1, pxhalf = wid >> 1;
  __shared__ __align__(16) ushort X_lds[348 * XSTRIDE];
  __shared__ __align__(16) ushort A_lds[128 * ASTRIDE];
  const float* xin = x + (size_t)n * IN_C * HW;
  int pbase[7];
#pragma unroll
  for (int b = 0; b < 7; b++) {
    int pxl = pxhalf * 112 + b * 16 + l16;
    int rl = pxl / 56;
    int col = pxl - rl * 56;
    pbase[b] = ((rl + 1) * 58 + (col + 1)) * XSTRIDE;
  }
  f32x4 acc[4][7];
#pragma unroll
  for (int a = 0; a < 4; a++)
#pragma unroll
    for (int b = 0; b < 7; b++) acc[a][b] = (f32x4){0.f, 0.f, 0.f, 0.f};
  for (int cc = 0; cc < 8; ++cc) {
    int c0 = cc * 32;
    __syncthreads();
    for (int e = t; e < 1392; e += 256) {
      int q = e / 348;
      int p = e - q * 348;
      int rl = p / 58;
      int cp = p - rl * 58;
      int y = rt * 4 - 1 + rl;
      int xx = cp - 1;
      float vv[8];
      if ((unsigned)y < 56u && (unsigned)xx < 56u) {
        const float* src = xin + (size_t)(c0 + q * 8) * HW + y * W_ + xx;
#pragma unroll
        for (int k = 0; k < 8; k++) vv[k] = src[(size_t)k * HW];
      } else {
#pragma unroll
        for (int k = 0; k < 8; k++) vv[k] = 0.f;
      }
      uint4 pk;
      pk.x = (uint)f2bf(vv[0]) | ((uint)f2bf(vv[1]) << 16);
      pk.y = (uint)f2bf(vv[2]) | ((uint)f2bf(vv[3]) << 16);
      pk.z = (uint)f2bf(vv[4]) | ((uint)f2bf(vv[5]) << 16);
      pk.w = (uint)f2bf(vv[6]) | ((uint)f2bf(vv[7]) << 16);
      *(uint4*)&X_lds[p * XSTRIDE + q * 8] = pk;
    }
    for (int kh = 0; kh < 3; ++kh) {
      __syncthreads();
      for (int e = t; e < 1536; e += 256) {
        int oc = e / 12;
        int seg = e - oc * 12;
        int tl = seg >> 2, q = seg & 3;
        uint4 v = *(const uint4*)(Wc + (size_t)(octile * 128 + oc) * D_ +
                                  (kh * 3 + tl) * IN_C + c0 + q * 8);
        *(uint4*)&A_lds[oc * ASTRIDE + tl * 32 + q * 8] = v;
      }
      __syncthreads();
      int di = kh - 1;
#pragma unroll
      for (int djj = 0; djj < 3; ++djj) {
        int poff = (di * 58 + (djj - 1)) * XSTRIDE + quad * 8;
        bf16x8 bfr[7];
#pragma unroll
        for (int b = 0; b < 7; b++) {
          union { uint4 u; bf16x8 v; } cv;
          cv.u = *(const uint4*)&X_lds[pbase[b] + poff];
          bfr[b] = cv.v;
        }
#pragma unroll
        for (int a = 0; a < 4; a++) {
          union { uint4 u; bf16x8 v; } cv;
          cv.u = *(const uint4*)&A_lds[(ochalf * 64 + a * 16 + l16) * ASTRIDE +
                                       djj * 32 + quad * 8];
          bf16x8 af = cv.v;
#pragma unroll
          for (int b = 0; b < 7; b++)
            acc[a][b] = __builtin_amdgcn_mfma_f32_16x16x32_bf16(af, bfr[b],
                                                                acc[a][b], 0, 0, 0);
        }
      }
    }
  }
  size_t nbase = (size_t)n * OUT_C * HW;
#pragma unroll
  for (int a = 0; a < 4; a++) {
#pragma unroll
    for (int r = 0; r < 4; r++) {
      int slot = octile * 128 + ochalf * 64 + a * 16 + quad * 4 + r;
      if (slot < cnt) {
        int oc = active[slot];
        float bv = bias[oc];
        size_t obase = nbase + (size_t)oc * HW + rt * 224 + pxhalf * 112 + l16;
#pragma unroll
        for (int b = 0; b < 7; b++)
          out[obase + b * 16] = acc[a][b][r] * sc + bv;
      }
    }
  }
}

extern "C" void kernel_launch(void* const* d_in, const int* in_sizes, int n_in,
                              void* d_out, int out_size, void* d_ws, size_t ws_size,
                              hipStream_t stream) {
  const float* x    = (const float*)d_in[0];
  const float* kern = (const float*)d_in[1];
  const float* bias = (const float*)d_in[2];
  const float* a    = (const float*)d_in[3];
  float* out = (float*)d_out;
  float* ws  = (float*)d_ws;

  const size_t need = 29933568ULL + 4 * 2304 * 4;  // Xb end + partials = 29,970,432

  if (ws_size >= need) {
    k_setup<<<dim3(5248), dim3(256), 0, stream>>>(x, kern, a, ws);
    k_route<<<dim3(1), dim3(512), 0, stream>>>(a, ws);
    k_prep<<<dim3(OUT_C), dim3(256), 0, stream>>>(kern, ws);
    k_convx<<<dim3(14, 4, 16), dim3(256), 0, stream>>>(bias, ws, out);
  } else {
    k_chanmax<<<dim3(IN_C), dim3(256), 0, stream>>>(x, ws);
    k_qhash<<<dim3(1), dim3(256), 0, stream>>>(a, ws);
    k_khash<<<dim3(OUT_C), dim3(256), 0, stream>>>(kern, a, ws);
    k_select<<<dim3(1), dim3(512), 0, stream>>>(ws);
    k_prep<<<dim3(OUT_C), dim3(256), 0, stream>>>(kern, ws);
    k_biasfill<<<dim3(4096), dim3(256), 0, stream>>>(bias, ws, out);
    k_conv<<<dim3(14, 4, 16), dim3(256), 0, stream>>>(x, bias, ws, out);
  }
}